// Round 14
// baseline (112.356 us; speedup 1.0000x reference)
//
#include <hip/hip_runtime.h>

// out = x + softmax((x@Wq) @ (rs@Wk)^T) @ (rs@Wv)
// B=4 T=8 N=2048 C=D=128 M=2048. fp32 in/out, fp16 MFMA compute (f32 accum).
// R12 = R11 + cross-tile rotation: PV1(t) deferred into t+1, fused 1:1 with
//       QK0(t+1) (two independent MFMA chains hide each other's latency).
//       V triple-buffered (80KB LDS). Barrier structure otherwise unchanged.

#define Bn 4
#define Tn 8
#define Nn 2048
#define Cn 128
#define Mn 2048
#define NTILES 32        // Mn/64
#define QROWS 128
#define NQT (Nn / QROWS) // 16

typedef __attribute__((ext_vector_type(4))) float f32x4;
typedef __attribute__((ext_vector_type(16))) float f32x16;
typedef __attribute__((ext_vector_type(8))) _Float16 f16x8;
typedef __attribute__((ext_vector_type(4))) unsigned int u32x4;
typedef __attribute__((address_space(3))) unsigned char lds_uc;
typedef const __attribute__((address_space(1))) unsigned char glb_uc;

__device__ __forceinline__ unsigned short f2h(float f) {
  _Float16 h = (_Float16)f;
  return __builtin_bit_cast(unsigned short, h);
}
__device__ __forceinline__ unsigned int pk2(float a, float b) {
  auto v = __builtin_amdgcn_cvt_pkrtz(a, b);
  return __builtin_bit_cast(unsigned int, v);
}
// 16B LDS read, 256B rows, swizzle (row&15)<<4
__device__ __forceinline__ f16x8 lds_read8w(const unsigned char* base, int row,
                                            int colByte) {
  int byte = row * 256 + (colByte ^ ((row & 15) << 4));
  return *(const f16x8*)(base + byte);
}
// 16B LDS read, 128B rows, swizzle (row&7)<<4
__device__ __forceinline__ f16x8 lds_read8v(const unsigned char* base, int row,
                                            int colByte) {
  int byte = row * 128 + (colByte ^ ((row & 7) << 4));
  return *(const f16x8*)(base + byte);
}
__device__ __forceinline__ void gld16(const void* g, void* l) {
  __builtin_amdgcn_global_load_lds((glb_uc*)g, (lds_uc*)l, 16, 0, 0);
}

// Build one PV B-frag (16 kv rows) from 8 P values in s[base..base+7].
// (mapping validated in R10: absmax matches fp16-precision expectation)
#define MKPF(dst, sv, base)                                        \
  {                                                                \
    unsigned a0 = pk2(sv[base + 0], sv[base + 1]);                 \
    unsigned b0 = pk2(sv[base + 4], sv[base + 5]);                 \
    unsigned a1 = pk2(sv[base + 2], sv[base + 3]);                 \
    unsigned b1 = pk2(sv[base + 6], sv[base + 7]);                 \
    asm("v_permlane32_swap_b32 %0, %1" : "+v"(a0), "+v"(b0));      \
    asm("v_permlane32_swap_b32 %0, %1" : "+v"(a1), "+v"(b1));      \
    u32x4 tmp = {a0, a1, b0, b1};                                  \
    dst = __builtin_bit_cast(f16x8, tmp);                          \
  }

// ---------------------------------------------------------------------------
// Kernel A: per (b,kt): K tile [64 kv][128 d] f16, 256B rows, swz (kv&15)<<4;
// V^T tile [128 d][64 m] f16, 128B rows, swz (d&7)<<4. Tiles 16KB each.
// grid: B*32 = 128 blocks, 256 threads. LDS 48KB.
// ---------------------------------------------------------------------------
__global__ __launch_bounds__(256) void proj_kv_kernel(
    const float* __restrict__ rs, const float* __restrict__ Wk,
    const float* __restrict__ Wv, unsigned short* __restrict__ k_ws,
    unsigned short* __restrict__ vt_ws) {
  __shared__ unsigned char smem[48 * 1024];
  unsigned char* rsh = smem;             // [64][128] f16 swz (16KB)
  unsigned char* wt = smem + 16 * 1024;  // [128][128] f16 swz, W^T (32KB)

  const int bid = blockIdx.x;
  const int b = bid >> 5;
  const int kt = bid & 31;
  const int m0 = kt << 6;
  const int tid = threadIdx.x;
  const int wv = tid >> 6, lane = tid & 63;

  {
    const float4* g = (const float4*)(rs + ((size_t)b * Mn + m0) * Cn);
#pragma unroll
    for (int i = 0; i < 8; ++i) {
      int f = tid + i * 256;
      int row = f >> 5, c4 = f & 31;
      float4 v = g[f];
      int byte = row * 256 + ((c4 * 8) ^ ((row & 15) << 4));
      *(ushort4*)(rsh + byte) =
          make_ushort4(f2h(v.x), f2h(v.y), f2h(v.z), f2h(v.w));
    }
  }

#define STAGE_WT(Wp)                                                          \
  {                                                                           \
    const float4* g = (const float4*)(Wp);                                    \
    _Pragma("unroll") for (int i = 0; i < 16; ++i) {                          \
      int f = tid + i * 256;                                                  \
      int cc = f >> 5, d0 = (f & 31) * 4;                                     \
      float4 v = g[f];                                                        \
      float vv[4] = {v.x, v.y, v.z, v.w};                                     \
      _Pragma("unroll") for (int j = 0; j < 4; ++j) {                         \
        int row = d0 + j;                                                     \
        int byte = row * 256 + ((cc * 2) ^ ((row & 15) << 4));                \
        *(unsigned short*)(wt + byte) = f2h(vv[j]);                           \
      }                                                                       \
    }                                                                         \
  }

  STAGE_WT(Wk);
  __syncthreads();

  const int arow = wv * 16 + (lane & 15);
  f16x8 ah[4];
#pragma unroll
  for (int ks = 0; ks < 4; ++ks)
    ah[ks] = lds_read8w(rsh, arow, (lane >> 4) * 16 + ks * 64);

  f32x4 acc[8];
#pragma unroll
  for (int df = 0; df < 8; ++df) acc[df] = (f32x4)(0.0f);
#pragma unroll
  for (int ks = 0; ks < 4; ++ks)
#pragma unroll
    for (int df = 0; df < 8; ++df) {
      f16x8 bf = lds_read8w(wt, df * 16 + (lane & 15), (lane >> 4) * 16 + ks * 64);
      acc[df] = __builtin_amdgcn_mfma_f32_16x16x32_f16(ah[ks], bf, acc[df], 0, 0, 0);
    }
  {
    unsigned char* kb = (unsigned char*)k_ws + ((size_t)b * NTILES + kt) * 16384;
#pragma unroll
    for (int df = 0; df < 8; ++df)
#pragma unroll
      for (int r = 0; r < 4; ++r) {
        int row = wv * 16 + (lane >> 4) * 4 + r;   // tile-local kv 0..63
        int dcol = df * 16 + (lane & 15);
        int byte = row * 256 + ((dcol * 2) ^ ((row & 15) << 4));
        *(unsigned short*)(kb + byte) = f2h(acc[df][r]);
      }
  }
  __syncthreads();

  STAGE_WT(Wv);
  __syncthreads();
#pragma unroll
  for (int df = 0; df < 8; ++df) acc[df] = (f32x4)(0.0f);
#pragma unroll
  for (int ks = 0; ks < 4; ++ks)
#pragma unroll
    for (int df = 0; df < 8; ++df) {
      f16x8 bf = lds_read8w(wt, df * 16 + (lane & 15), (lane >> 4) * 16 + ks * 64);
      acc[df] = __builtin_amdgcn_mfma_f32_16x16x32_f16(ah[ks], bf, acc[df], 0, 0, 0);
    }
  {
    unsigned char* vb = (unsigned char*)vt_ws + ((size_t)b * NTILES + kt) * 16384;
#pragma unroll
    for (int df = 0; df < 8; ++df)
#pragma unroll
      for (int r = 0; r < 4; ++r) {
        int row = wv * 16 + (lane >> 4) * 4 + r;   // tile-local m
        int dcol = df * 16 + (lane & 15);          // d (row of V^T tile)
        int byte = dcol * 128 + ((row * 2) ^ ((dcol & 7) << 4));
        *(unsigned short*)(vb + byte) = f2h(acc[df][r]);
      }
  }
#undef STAGE_WT
}

// ---------------------------------------------------------------------------
// Kernel B: flash attention, 32x32 MFMA, in-register P, cross-tile rotation.
// grid 512 x 256 thr (4 waves x 32 q-rows). LDS 80KB:
//  prologue: xa/q [128][256B] @0 (32K), wq^T @32K (32K)
//  main: K[2] @0/16K, V[3] @32K/48K/64K
//  epilogue: O bounce [128 q][512B] @0 (64K, after barrier)
// ---------------------------------------------------------------------------
__global__ __launch_bounds__(256, 2) void attn_kernel(
    const float* __restrict__ x, const float* __restrict__ Wq,
    const unsigned short* __restrict__ k_ws,
    const unsigned short* __restrict__ vt_ws, float* __restrict__ out) {
  __shared__ unsigned char smem[80 * 1024];

  const int bx = blockIdx.x;
  const int wb = ((bx & 7) << 6) | (bx >> 3);  // XCD swizzle (512 % 8 == 0)
  const int b = wb >> 7;
  const int t_ = (wb >> 4) & 7;
  const int n0 = (wb & 15) * QROWS;
  const int tid = threadIdx.x;
  const int wv = tid >> 6, lane = tid & 63;
  const int c = lane & 15, g = lane >> 4;
  const int l31 = lane & 31, hi = lane >> 5;

  const float* xg = x + (((size_t)b * Tn + t_) * Nn + n0) * Cn;  // 128x128
  unsigned char* xa = smem;
  unsigned char* wqb = smem + 32 * 1024;

  // ---- prologue: q = x@Wq (f16) * log2e (16x16 path) ----
  const float LOG2E = 1.4426950408889634f;
  {
    const float4* gp = (const float4*)xg;
#pragma unroll
    for (int ii = 0; ii < 16; ++ii) {
      int f = tid + ii * 256;
      int row = f >> 5, c4 = f & 31;
      float4 v = gp[f];
      int byte = row * 256 + ((c4 * 8) ^ ((row & 15) << 4));
      *(ushort4*)(xa + byte) =
          make_ushort4(f2h(v.x), f2h(v.y), f2h(v.z), f2h(v.w));
    }
  }
  {
    const float4* gp = (const float4*)Wq;
#pragma unroll
    for (int ii = 0; ii < 16; ++ii) {
      int f = tid + ii * 256;
      int cc = f >> 5, d0 = (f & 31) * 4;
      float4 v = gp[f];
      float vv[4] = {v.x, v.y, v.z, v.w};
#pragma unroll
      for (int j = 0; j < 4; ++j) {
        int row = d0 + j;
        int byte = row * 256 + ((cc * 2) ^ ((row & 15) << 4));
        *(unsigned short*)(wqb + byte) = f2h(vv[j] * LOG2E);
      }
    }
  }
  __syncthreads();

  {
    f32x4 qacc[2][8];
#pragma unroll
    for (int rb = 0; rb < 2; ++rb)
#pragma unroll
      for (int df = 0; df < 8; ++df) qacc[rb][df] = (f32x4)(0.0f);
    f16x8 xf[2][4];
#pragma unroll
    for (int rb = 0; rb < 2; ++rb)
#pragma unroll
      for (int ks = 0; ks < 4; ++ks)
        xf[rb][ks] = lds_read8w(xa, wv * 32 + rb * 16 + c, g * 16 + ks * 64);
#pragma unroll
    for (int ks = 0; ks < 4; ++ks)
#pragma unroll
      for (int df = 0; df < 8; ++df) {
        f16x8 bf = lds_read8w(wqb, df * 16 + c, g * 16 + ks * 64);
        qacc[0][df] = __builtin_amdgcn_mfma_f32_16x16x32_f16(xf[0][ks], bf, qacc[0][df], 0, 0, 0);
        qacc[1][df] = __builtin_amdgcn_mfma_f32_16x16x32_f16(xf[1][ks], bf, qacc[1][df], 0, 0, 0);
      }
    // write q (f16) into own rows of xa (wave-local; in-wave ordering)
#pragma unroll
    for (int rb = 0; rb < 2; ++rb)
#pragma unroll
      for (int df = 0; df < 8; ++df)
#pragma unroll
        for (int r = 0; r < 4; ++r) {
          int row = wv * 32 + rb * 16 + g * 4 + r;
          int col = df * 16 + c;
          int byte = row * 256 + ((col * 2) ^ ((row & 15) << 4));
          *(unsigned short*)(xa + byte) = f2h(qacc[rb][df][r]);
        }
  }
  // read q as 32x32 B-frags: lane holds col q=l31, rows d = kc*16+hi*8..+7
  f16x8 qf[8];
#pragma unroll
  for (int kc = 0; kc < 8; ++kc)
    qf[kc] = lds_read8w(xa, wv * 32 + l31, kc * 32 + hi * 16);
  __syncthreads();  // xa/wqb dead; K/V staging takes over

  // ---- main flash loop ----
  f32x16 o[4];
#pragma unroll
  for (int dblk = 0; dblk < 4; ++dblk) o[dblk] = (f32x16)(0.0f);
  float mrow = -INFINITY;
  float lrow = 0.f;  // per-lane partial (hi halves merged at end)

  const unsigned char* khg = (const unsigned char*)k_ws + (size_t)b * NTILES * 16384;
  const unsigned char* vtg = (const unsigned char*)vt_ws + (size_t)b * NTILES * 16384;

  auto stage = [&](int t) {
    unsigned char* kd = smem + (t & 1) * 16384 + tid * 16;
    unsigned char* vd = smem + 32 * 1024 + (t % 3) * 16384 + tid * 16;
    const unsigned char* ksrc = khg + (size_t)t * 16384 + tid * 16;
    const unsigned char* vsrc = vtg + (size_t)t * 16384 + tid * 16;
#pragma unroll
    for (int h = 0; h < 4; ++h) {
      gld16(ksrc + h * 4096, kd + h * 4096);
      gld16(vsrc + h * 4096, vd + h * 4096);
    }
  };

  // softmax for one 32-kv subtile held in s (16 regs + partner lane's 16)
  auto softmax_sub = [&](f32x16& s, f16x8& pfA, f16x8& pfB) {
    float mx[8];
#pragma unroll
    for (int r = 0; r < 8; ++r) mx[r] = fmaxf(s[r], s[r + 8]);
#pragma unroll
    for (int r = 0; r < 4; ++r) mx[r] = fmaxf(mx[r], mx[r + 4]);
    float tm = fmaxf(fmaxf(mx[0], mx[1]), fmaxf(mx[2], mx[3]));
    tm = fmaxf(tm, __shfl_xor(tm, 32));
    if (__any(tm > mrow + 8.f)) {  // rare rescale path
      float newm = fmaxf(mrow, tm);
      float scl = __builtin_amdgcn_exp2f(mrow - newm);
#pragma unroll
      for (int dblk = 0; dblk < 4; ++dblk) o[dblk] *= scl;
      lrow *= scl;
      mrow = newm;
    }
    float p[16];
#pragma unroll
    for (int r = 0; r < 16; ++r) p[r] = __builtin_amdgcn_exp2f(s[r] - mrow);
    float ps = 0.f;
    {
      float a[8];
#pragma unroll
      for (int r = 0; r < 8; ++r) a[r] = p[r] + p[r + 8];
#pragma unroll
      for (int r = 0; r < 4; ++r) a[r] += a[r + 4];
      ps = (a[0] + a[1]) + (a[2] + a[3]);
    }
    lrow += ps;
#pragma unroll
    for (int r = 0; r < 16; ++r) s[r] = p[r];
    MKPF(pfA, s, 0);
    MKPF(pfB, s, 8);
  };

  stage(0);
  __syncthreads();

  f16x8 pf2p, pf3p;  // PV-subtile-1 fragments carried from previous tile
#pragma unroll 1
  for (int t = 0; t < NTILES; ++t) {
    unsigned char* kb = smem + (t & 1) * 16384;
    unsigned char* vb = smem + 32 * 1024 + (t % 3) * 16384;
    unsigned char* vbp = smem + 32 * 1024 + ((t + 2) % 3) * 16384;  // (t-1)%3

    // --- fused: QK^T sub0 (t) interleaved 1:1 with PV sub1 (t-1) ---
    f32x16 s0 = (f32x16)(0.0f);
    __builtin_amdgcn_s_setprio(1);
#pragma unroll
    for (int i = 0; i < 8; ++i) {
      f16x8 kf0 = lds_read8w(kb, l31, i * 32 + hi * 16);
      s0 = __builtin_amdgcn_mfma_f32_32x32x16_f16(kf0, qf[i], s0, 0, 0, 0);
      if (t > 0) {
        int dblk = i >> 1, half = i & 1;
        f16x8 vf = lds_read8v(vbp, dblk * 32 + l31, (2 + half) * 32 + hi * 16);
        o[dblk] = __builtin_amdgcn_mfma_f32_32x32x16_f16(
            vf, half ? pf3p : pf2p, o[dblk], 0, 0, 0);
      }
    }
    __builtin_amdgcn_s_setprio(0);

    // start next-tile DMA
    if (t + 1 < NTILES) stage(t + 1);

    // --- QK^T sub1 (t) issues; softmax0 overlaps on VALU ---
    f32x16 s1 = (f32x16)(0.0f);
    __builtin_amdgcn_s_setprio(1);
#pragma unroll
    for (int kc = 0; kc < 8; ++kc) {
      f16x8 kf1 = lds_read8w(kb, 32 + l31, kc * 32 + hi * 16);
      s1 = __builtin_amdgcn_mfma_f32_32x32x16_f16(kf1, qf[kc], s1, 0, 0, 0);
    }
    __builtin_amdgcn_s_setprio(0);

    f16x8 pf0, pf1;
    softmax_sub(s0, pf0, pf1);  // VALU, overlaps s1 MFMA latency

    // --- PV sub0 (t); softmax1 overlaps ---
    __builtin_amdgcn_s_setprio(1);
#pragma unroll
    for (int dblk = 0; dblk < 4; ++dblk) {
      f16x8 vf0 = lds_read8v(vb, dblk * 32 + l31, 0 * 32 + hi * 16);
      f16x8 vf1 = lds_read8v(vb, dblk * 32 + l31, 1 * 32 + hi * 16);
      o[dblk] = __builtin_amdgcn_mfma_f32_32x32x16_f16(vf0, pf0, o[dblk], 0, 0, 0);
      o[dblk] = __builtin_amdgcn_mfma_f32_32x32x16_f16(vf1, pf1, o[dblk], 0, 0, 0);
    }
    __builtin_amdgcn_s_setprio(0);

    softmax_sub(s1, pf2p, pf3p);  // VALU, overlaps PV0; PV1 deferred to t+1
    __syncthreads();
  }

  // --- tail: PV sub1 of last tile ---
  {
    unsigned char* vbp = smem + 32 * 1024 + ((NTILES - 1) % 3) * 16384;
#pragma unroll
    for (int dblk = 0; dblk < 4; ++dblk) {
      f16x8 vf2 = lds_read8v(vbp, dblk * 32 + l31, 2 * 32 + hi * 16);
      f16x8 vf3 = lds_read8v(vbp, dblk * 32 + l31, 3 * 32 + hi * 16);
      o[dblk] = __builtin_amdgcn_mfma_f32_32x32x16_f16(vf2, pf2p, o[dblk], 0, 0, 0);
      o[dblk] = __builtin_amdgcn_mfma_f32_32x32x16_f16(vf3, pf3p, o[dblk], 0, 0, 0);
    }
  }
  __syncthreads();  // all waves done reading V before bounce overwrites smem

  // ---- epilogue: merge hi halves of l, bounce O via LDS, out = x + O/l ----
  lrow += __shfl_xor(lrow, 32);
  float inv = 1.0f / lrow;
#pragma unroll
  for (int dblk = 0; dblk < 4; ++dblk)
#pragma unroll
    for (int rg = 0; rg < 4; ++rg) {
      f32x4 v;
      v[0] = o[dblk][rg * 4 + 0] * inv;
      v[1] = o[dblk][rg * 4 + 1] * inv;
      v[2] = o[dblk][rg * 4 + 2] * inv;
      v[3] = o[dblk][rg * 4 + 3] * inv;
      int row = wv * 32 + l31;
      int colb = dblk * 128 + rg * 32 + hi * 16;
      int byte = row * 512 + (colb ^ ((row & 7) << 4));
      *(f32x4*)(smem + byte) = v;
    }
  __syncthreads();
  {
    const float4* xg4 = (const float4*)xg;
    float4* og4 = (float4*)(out + (((size_t)b * Tn + t_) * Nn + n0) * Cn);
#pragma unroll
    for (int ii = 0; ii < 16; ++ii) {
      int f = tid + ii * 256;
      int row = f >> 5, slot = f & 31;
      int byte = row * 512 + ((slot * 16) ^ ((row & 7) << 4));
      f32x4 v = *(const f32x4*)(smem + byte);
      float4 xv = xg4[f];
      og4[f] = make_float4(xv.x + v[0], xv.y + v[1], xv.z + v[2], xv.w + v[3]);
    }
  }
}

extern "C" void kernel_launch(void* const* d_in, const int* in_sizes, int n_in,
                              void* d_out, int out_size, void* d_ws,
                              size_t ws_size, hipStream_t stream) {
  const float* x = (const float*)d_in[0];
  const float* rs = (const float*)d_in[1];
  const float* Wq = (const float*)d_in[2];
  const float* Wk = (const float*)d_in[3];
  const float* Wv = (const float*)d_in[4];
  float* out = (float*)d_out;

  // ws: K f16 tiles [B][32][16KB] (2MB) | V^T tiles [B][32][16KB] (2MB)
  unsigned short* k_ws = (unsigned short*)d_ws;
  unsigned short* vt_ws = k_ws + (size_t)Bn * Mn * Cn;

  proj_kv_kernel<<<Bn * NTILES, 256, 0, stream>>>(rs, Wk, Wv, k_ws, vt_ws);
  attn_kernel<<<Bn * Tn * NQT, 256, 0, stream>>>(x, Wq, k_ws, vt_ws, out);
}